// Round 1
// baseline (534.640 us; speedup 1.0000x reference)
//
#include <hip/hip_runtime.h>
#include <math.h>

// mLSTM block: B=64, IN=512, H=1024
// out = [h_t (64*1024) | C_t (64*1024*1024) | n_t (64*1024)] f32
// ws  = [q|k|v|i|f|o|retrieved] each 64*1024 f32  (1.75 MB)

constexpr int kB  = 64;
constexpr int kIN = 512;
constexpr int kH  = 1024;
constexpr int kBH = kB * kH;   // 65536

// ---------------------------------------------------------------------------
// Kernel 1: all six projections + activations.
// grid = 192 blocks x 256 thr. Each wave handles 8 consecutive output columns
// (j = bx*32 + wave*8 + u), lane = batch row b. x chunk staged in LDS k-major
// [128][65] (pad -> conflict-free inner reads). W rows are wave-uniform
// (readfirstlane) -> scalar loads. 8 accumulators amortize each LDS read.
// ---------------------------------------------------------------------------
__global__ __launch_bounds__(256) void gates_kernel(
    const float* __restrict__ x,
    const float* __restrict__ Wq, const float* __restrict__ Wk,
    const float* __restrict__ Wv, const float* __restrict__ Wi,
    const float* __restrict__ Wf, const float* __restrict__ Wo,
    const float* __restrict__ bi, const float* __restrict__ bfv,
    const float* __restrict__ bo,
    float* __restrict__ ws)
{
    __shared__ float xs[128][65];
    const int tid  = threadIdx.x;
    const int lane = tid & 63;            // = batch row b
    const int wid  = tid >> 6;
    const int j0   = __builtin_amdgcn_readfirstlane((int)blockIdx.x * 32 + wid * 8);
    const int m       = j0 >> 10;         // which of the 6 matrices (uniform per block)
    const int colbase = j0 & 1023;
    const float* Wm = (m == 0) ? Wq : (m == 1) ? Wk : (m == 2) ? Wv
                    : (m == 3) ? Wi : (m == 4) ? Wf : Wo;
    const float* wbase = Wm + colbase * kIN;   // 8 contiguous W rows

    float acc[8];
#pragma unroll
    for (int u = 0; u < 8; ++u) acc[u] = 0.f;

    for (int k0 = 0; k0 < kIN; k0 += 128) {
        __syncthreads();                       // protect previous chunk
        // stage x[:, k0:k0+128] k-major: xs[k][b]
#pragma unroll
        for (int p = 0; p < 8; ++p) {
            int l  = p * 1024 + tid * 4;
            int bb = l >> 7;                   // 0..63
            int cc = l & 127;
            float4 xv = *reinterpret_cast<const float4*>(x + bb * kIN + k0 + cc);
            xs[cc + 0][bb] = xv.x;
            xs[cc + 1][bb] = xv.y;
            xs[cc + 2][bb] = xv.z;
            xs[cc + 3][bb] = xv.w;
        }
        __syncthreads();
#pragma unroll 16
        for (int k = 0; k < 128; ++k) {
            float xv = xs[k][lane];            // conflict-free (pad 65)
#pragma unroll
            for (int u = 0; u < 8; ++u)
                acc[u] = fmaf(wbase[u * kIN + k0 + k], xv, acc[u]); // s_load (uniform)
        }
    }

    const float scale = 0.03125f;              // 1/sqrt(1024)
#pragma unroll
    for (int u = 0; u < 8; ++u) {
        const int col = colbase + u;
        const int idx = lane * kH + col;
        const float a = acc[u];
        if (m == 0)      ws[0 * kBH + idx] = a * scale;                       // q
        else if (m == 1) ws[1 * kBH + idx] = a * scale;                       // k
        else if (m == 2) ws[2 * kBH + idx] = a;                               // v
        else if (m == 3) ws[3 * kBH + idx] = __expf(a + bi[col]);             // i
        else if (m == 4) ws[4 * kBH + idx] = 1.f / (1.f + __expf(-(a + bfv[col]))); // f
        else             ws[5 * kBH + idx] = 1.f / (1.f + __expf(-(a + bo[col])));  // o
    }
}

// ---------------------------------------------------------------------------
// Kernel 2: C_t = f*C_prev + (i*v)*k  (outer product), fused retrieved = C_t.q
// 1 wave per C row (b,v). 4 rows per block, all same b -> q,k staged once.
// Coalesced float4 on the 537 MB C stream; this kernel IS the roofline.
// ---------------------------------------------------------------------------
__global__ __launch_bounds__(256) void cell_kernel(
    const float* __restrict__ C_prev,
    const float* __restrict__ ws,
    float* __restrict__ C_out,
    float* __restrict__ retr)
{
    __shared__ float qs[kH];
    __shared__ float ks[kH];
    const int tid  = threadIdx.x;
    const int lane = tid & 63;
    const int wid  = tid >> 6;
    const int row  = (int)blockIdx.x * 4 + wid;   // = b*1024 + v
    const int b    = row >> 10;                   // uniform per block (1024 % 4 == 0)

    {
        const int c = tid * 4;
        *reinterpret_cast<float4*>(&qs[c]) =
            *reinterpret_cast<const float4*>(ws + 0 * kBH + b * kH + c);
        *reinterpret_cast<float4*>(&ks[c]) =
            *reinterpret_cast<const float4*>(ws + 1 * kBH + b * kH + c);
    }
    __syncthreads();

    const float fv  = ws[4 * kBH + row];
    const float ivv = ws[3 * kBH + row] * ws[2 * kBH + row];  // i_t * v_t
    const float* Crow = C_prev + (size_t)row * kH;
    float*       Orow = C_out  + (size_t)row * kH;

    float acc = 0.f;
#pragma unroll
    for (int it = 0; it < 4; ++it) {
        const int idx = it * 256 + lane * 4;
        float4 c  = *reinterpret_cast<const float4*>(Crow + idx);
        float4 kf = *reinterpret_cast<const float4*>(&ks[idx]);
        float4 qf = *reinterpret_cast<const float4*>(&qs[idx]);
        float4 cn;
        cn.x = fmaf(fv, c.x, ivv * kf.x);
        cn.y = fmaf(fv, c.y, ivv * kf.y);
        cn.z = fmaf(fv, c.z, ivv * kf.z);
        cn.w = fmaf(fv, c.w, ivv * kf.w);
        *reinterpret_cast<float4*>(Orow + idx) = cn;
        acc = fmaf(cn.x, qf.x, acc);
        acc = fmaf(cn.y, qf.y, acc);
        acc = fmaf(cn.z, qf.z, acc);
        acc = fmaf(cn.w, qf.w, acc);
    }
#pragma unroll
    for (int off = 32; off > 0; off >>= 1)
        acc += __shfl_down(acc, off, 64);
    if (lane == 0) retr[row] = acc;
}

// ---------------------------------------------------------------------------
// Kernel 3: n_t, normalizer (per-b reduction), h_t. One block per b.
// ---------------------------------------------------------------------------
__global__ __launch_bounds__(256) void finish_kernel(
    const float* __restrict__ n_prev,
    const float* __restrict__ ws,
    float* __restrict__ out)
{
    __shared__ float red[4];
    const int b    = blockIdx.x;
    const int tid  = threadIdx.x;
    const int base = b * kH + tid * 4;

    float4 f4 = *reinterpret_cast<const float4*>(ws + 4 * kBH + base);
    float4 i4 = *reinterpret_cast<const float4*>(ws + 3 * kBH + base);
    float4 k4 = *reinterpret_cast<const float4*>(ws + 1 * kBH + base);
    float4 q4 = *reinterpret_cast<const float4*>(ws + 0 * kBH + base);
    float4 np = *reinterpret_cast<const float4*>(n_prev + base);

    float4 nt;
    nt.x = fmaf(f4.x, np.x, i4.x * k4.x);
    nt.y = fmaf(f4.y, np.y, i4.y * k4.y);
    nt.z = fmaf(f4.z, np.z, i4.z * k4.z);
    nt.w = fmaf(f4.w, np.w, i4.w * k4.w);
    *reinterpret_cast<float4*>(out + kBH + (size_t)kB * kH * kH + base) = nt; // n_t

    float part = nt.x * q4.x + nt.y * q4.y + nt.z * q4.z + nt.w * q4.w;
#pragma unroll
    for (int off = 32; off > 0; off >>= 1)
        part += __shfl_down(part, off, 64);
    if ((tid & 63) == 0) red[tid >> 6] = part;
    __syncthreads();
    const float total = red[0] + red[1] + red[2] + red[3];
    const float norm  = fmaxf(fabsf(total), 1.0f);

    float4 o4 = *reinterpret_cast<const float4*>(ws + 5 * kBH + base);
    float4 r4 = *reinterpret_cast<const float4*>(ws + 6 * kBH + base);
    float4 h;
    h.x = o4.x * r4.x / norm;
    h.y = o4.y * r4.y / norm;
    h.z = o4.z * r4.z / norm;
    h.w = o4.w * r4.w / norm;
    *reinterpret_cast<float4*>(out + base) = h;   // h_t
}

// ---------------------------------------------------------------------------
extern "C" void kernel_launch(void* const* d_in, const int* in_sizes, int n_in,
                              void* d_out, int out_size, void* d_ws, size_t ws_size,
                              hipStream_t stream) {
    const float* x      = (const float*)d_in[0];
    // d_in[1] = h_prev (unused by the reference math)
    const float* C_prev = (const float*)d_in[2];
    const float* n_prev = (const float*)d_in[3];
    const float* Wq = (const float*)d_in[4];
    const float* Wk = (const float*)d_in[5];
    const float* Wv = (const float*)d_in[6];
    const float* Wi = (const float*)d_in[7];
    const float* Wf = (const float*)d_in[8];
    const float* Wo = (const float*)d_in[9];
    const float* bi = (const float*)d_in[10];
    const float* bf = (const float*)d_in[11];
    const float* bo = (const float*)d_in[12];
    float* out = (float*)d_out;
    float* ws  = (float*)d_ws;   // needs 7*65536*4 = 1.75 MB

    gates_kernel<<<192, 256, 0, stream>>>(x, Wq, Wk, Wv, Wi, Wf, Wo, bi, bf, bo, ws);
    cell_kernel<<<kBH / 4, 256, 0, stream>>>(C_prev, ws, out + kBH, ws + 6 * kBH);
    finish_kernel<<<kB, 256, 0, stream>>>(n_prev, ws, out);
}